// Round 5
// baseline (301.750 us; speedup 1.0000x reference)
//
#include <hip/hip_runtime.h>

// ---------------------------------------------------------------------------
// HolographicMemory: out = softmax( x @ [Kr|Ki]^T * temp ) @ [Vr|Vi]
// v6: byte-cutting via taller wave tiles (128 rows x 64 cols per wave,
//     acc stays 128 regs). Panel (K/V) traffic halves; gemm2 A-amplification
//     8x -> 2x. Schedules identical to v5 with recounted vmcnt.
//   energy: 128 rows x 512 cols per block, 8 waves; K reg-direct (4 frags),
//           X reg->LDS staged; per-step VMW(6)/VMW(4)/WAITBAR(6).
//   gemm2:  128 rows x 512 cols per block, 8 waves; 4x8KB A buffers,
//           B reg-direct; per-body VMWBAR(5). XCD swizzle (grid 512).
// ---------------------------------------------------------------------------

#define DIMX   1024
#define MEMN   512
#define NROWS  32768
#define TEMP   0.04419417382415922f  // 512^-0.5

typedef __bf16 bf16;
typedef __bf16 bf16x8 __attribute__((ext_vector_type(8)));
typedef float  f32x4  __attribute__((ext_vector_type(4)));

__device__ __forceinline__ void gload_lds16(const void* g, void* l) {
    __builtin_amdgcn_global_load_lds(
        (const __attribute__((address_space(1))) unsigned*)g,
        (__attribute__((address_space(3))) unsigned*)l,
        16, 0, 0);
}
__device__ __forceinline__ void gl_b16x8(bf16x8& d, const bf16* p) {
    asm volatile("global_load_dwordx4 %0, %1, off" : "=v"(d) : "v"(p));
}
__device__ __forceinline__ void gl_f32x4(f32x4& d, const float* p) {
    asm volatile("global_load_dwordx4 %0, %1, off" : "=v"(d) : "v"(p));
}
#define VMW(N)     do { asm volatile("s_waitcnt vmcnt(" #N ")" ::: "memory"); \
                        __builtin_amdgcn_sched_barrier(0); } while (0)
#define WAITBAR(N) do { asm volatile("s_waitcnt vmcnt(" #N ") lgkmcnt(0)\n\t" \
                        "s_barrier" ::: "memory");                            \
                        __builtin_amdgcn_sched_barrier(0); } while (0)
#define VMWBAR(N)  do { asm volatile("s_waitcnt vmcnt(" #N ")\n\t"            \
                        "s_barrier" ::: "memory");                            \
                        __builtin_amdgcn_sched_barrier(0); } while (0)

// ---- pack K' and V'^T in MFMA-fragment order (unchanged layouts) ----------
// Kb_f[c][t][l][e]: element (row=t*16+lm, k=c*32+g*8+e) of K'=[Kr|Ki]
// Vb_f[c][t][l][e]: element (n=t*16+lm, k=c*32+g*8+e) of V'^T [1024][512]
__global__ __launch_bounds__(256) void pack_kv_kernel(const float* __restrict__ kr,
                                                      const float* __restrict__ ki,
                                                      const float* __restrict__ vr,
                                                      const float* __restrict__ vi,
                                                      bf16* __restrict__ Kb,
                                                      bf16* __restrict__ Vb) {
    const int idx = blockIdx.x * 256 + threadIdx.x;   // 0 .. 2^19-1
    const int e = idx & 7, l = (idx >> 3) & 63;
    const int lm = l & 15, g = l >> 4;
    {   // Kb_f
        const int t = (idx >> 9) & 31, c = idx >> 14;
        const int row = t * 16 + lm, k = c * 32 + g * 8 + e;
        const float v = (k < 512) ? kr[row * 512 + k] : ki[row * 512 + (k - 512)];
        Kb[idx] = (bf16)v;
    }
    {   // Vb_f
        const int t = (idx >> 9) & 63, c = idx >> 15;
        const int h = t * 16 + lm, m = c * 32 + g * 8 + e;
        const float v = (h < 512) ? vr[m * 512 + h] : vi[m * 512 + (h - 512)];
        Vb[idx] = (bf16)v;
    }
}

// ---------------------------------------------------------------------------
// Fused energy + softmax. Block: 128 rows x 512 cols, 512 threads (8 waves);
// wave wv owns cols wv*64..+63 over ALL 128 rows -> acc[8][4] f32x4.
// K per wave per step = 4 frag loads (4KB); X staged to 2x8KB LDS.
// ---------------------------------------------------------------------------
__global__ __launch_bounds__(512, 2) void energy_softmax_kernel(
        const float* __restrict__ x,    // [32768][1024] fp32
        const bf16*  __restrict__ Kb,   // fragment-order, 1 MiB
        bf16* __restrict__ attn) {      // [32768][512] bf16 out
    __shared__ __align__(16) bf16 Xs[2][128 * 32];
    __shared__ float red[128][8][2];    // [row][wave][{max,sum}]

    const int tid  = threadIdx.x;
    const int wv   = tid >> 6, lane = tid & 63;
    const int lm   = lane & 15, g = lane >> 4;
    const int rowB = blockIdx.x * 128;

    // X staging: thread -> row sr (0..127), 16B chunk sc (0..3)
    const int sr = tid >> 2, sc = tid & 3;
    const float* xsrc = x + (size_t)(rowB + sr) * DIMX + sc * 8;
    const int xw_off = sr * 64 + ((sc ^ ((sr >> 1) & 3)) << 4);   // bytes

    // K fragments: wave's col-tiles are Kb mem-tiles wv*4 + j
    const bf16* kbase = Kb + (wv * 4) * 512 + lane * 8;

    f32x4 acc[8][4] = {};
    f32x4 xa, xb;
    bf16x8 kf0[4], kf1[4];

#define K_PREF(DST, C) { _Pragma("unroll") for (int j = 0; j < 4; ++j)         \
        gl_b16x8(DST[j], kbase + (size_t)(C) * 16384 + j * 512); }
#define X_PREF(S) { gl_f32x4(xa, xsrc + (S) * 32);                             \
                    gl_f32x4(xb, xsrc + (S) * 32 + 4); }
#define X_WR(B) { bf16x8 w;                                                    \
    w[0]=(bf16)xa[0]; w[1]=(bf16)xa[1]; w[2]=(bf16)xa[2]; w[3]=(bf16)xa[3];    \
    w[4]=(bf16)xb[0]; w[5]=(bf16)xb[1]; w[6]=(bf16)xb[2]; w[7]=(bf16)xb[3];    \
    *(bf16x8*)((char*)Xs[B] + xw_off) = w; }
#define COMPUTE_E(XB, KF) { bf16x8 af[8];                                      \
    _Pragma("unroll") for (int i = 0; i < 8; ++i) { const int r = i * 16 + lm; \
        af[i] = *(const bf16x8*)((const char*)Xs[XB] + r * 64                  \
                                 + ((g ^ ((r >> 1) & 3)) << 4)); }             \
    __builtin_amdgcn_s_setprio(1);                                             \
    _Pragma("unroll") for (int i = 0; i < 8; ++i)                              \
        _Pragma("unroll") for (int j = 0; j < 4; ++j)                          \
            acc[i][j] = __builtin_amdgcn_mfma_f32_16x16x32_bf16(               \
                af[i], KF[j], acc[i][j], 0, 0, 0);                             \
    __builtin_amdgcn_s_setprio(0); }
// steady step t: entry queue = [K(t)4, X(t+1)2]
#define STEP_E(KCUR, KNXT, XB, CH_K, CH_X)                                     \
    K_PREF(KNXT, CH_K);            /* -> 10 in flight */                       \
    VMW(6);                        /* retire K(t): full-step coverage */       \
    COMPUTE_E(XB, KCUR);                                                       \
    VMW(4);                        /* retire X(t+1) */                         \
    X_WR((XB) ^ 1);                                                            \
    X_PREF(CH_X);                  /* -> 6 in flight */                        \
    WAITBAR(6);                    /* barrier only: waits nothing */

    // ---- prologue -----------------------------------------------------------
    X_PREF(0);                 // [X0:2]
    K_PREF(kf0, 0);            // [6]
    VMW(4);  X_WR(0);          // X0 -> Xs[0]
    X_PREF(1);                 // [K0:4, X1:2]
    WAITBAR(6);                // barrier only

    // ---- steps 0..29 (unroll 2: kf/Xs parity) -------------------------------
    for (int t = 0; t < 30; t += 2) {
        STEP_E(kf0, kf1, 0, t + 1, t + 2);
        STEP_E(kf1, kf0, 1, t + 2, t + 3);
    }
    // ---- step 30 ------------------------------------------------------------
    K_PREF(kf1, 31);           // [K30:4, X31:2, K31:4]
    VMW(6);                    // retire K30
    COMPUTE_E(0, kf0);
    VMW(4);                    // retire X31
    X_WR(1);
    WAITBAR(4);                // barrier; K31 stays in flight
    // ---- step 31 ------------------------------------------------------------
    VMW(0);                    // retire K31
    COMPUTE_E(1, kf1);

#undef K_PREF
#undef X_PREF
#undef X_WR
#undef COMPUTE_E
#undef STEP_E

    // ---- softmax epilogue ---------------------------------------------------
    // C/D layout: col = j*16 + lm (+wv*64), row = i*16 + g*4 + reg (0..127).
    float fac[8][4];
    #pragma unroll
    for (int i = 0; i < 8; ++i) {
        #pragma unroll
        for (int rg = 0; rg < 4; ++rg) {
            float m = acc[i][0][rg] * TEMP;
            #pragma unroll
            for (int j = 1; j < 4; ++j) m = fmaxf(m, acc[i][j][rg] * TEMP);
            m = fmaxf(m, __shfl_xor(m, 1));
            m = fmaxf(m, __shfl_xor(m, 2));
            m = fmaxf(m, __shfl_xor(m, 4));
            m = fmaxf(m, __shfl_xor(m, 8));
            float s = 0.f;
            #pragma unroll
            for (int j = 0; j < 4; ++j) {
                const float v = __expf(acc[i][j][rg] * TEMP - m);
                acc[i][j][rg] = v;
                s += v;
            }
            s += __shfl_xor(s, 1);
            s += __shfl_xor(s, 2);
            s += __shfl_xor(s, 4);
            s += __shfl_xor(s, 8);
            const int rr = i * 16 + g * 4 + rg;
            if (lm == 0) { red[rr][wv][0] = m; red[rr][wv][1] = s; }
            fac[i][rg] = m;
        }
    }
    __syncthreads();
    #pragma unroll
    for (int i = 0; i < 8; ++i) {
        #pragma unroll
        for (int rg = 0; rg < 4; ++rg) {
            const int rr = i * 16 + g * 4 + rg;
            float M = red[rr][0][0];
            #pragma unroll
            for (int w = 1; w < 8; ++w) M = fmaxf(M, red[rr][w][0]);
            float S = 0.f;
            #pragma unroll
            for (int w = 0; w < 8; ++w)
                S += red[rr][w][1] * __expf(red[rr][w][0] - M);
            fac[i][rg] = __expf(fac[i][rg] - M) / S;
        }
    }
    #pragma unroll
    for (int i = 0; i < 8; ++i) {
        #pragma unroll
        for (int rg = 0; rg < 4; ++rg) {
            const size_t rr = (size_t)(rowB + i * 16 + g * 4 + rg);
            bf16* p = attn + rr * MEMN + wv * 64 + lm;
            const float f = fac[i][rg];
            #pragma unroll
            for (int j = 0; j < 4; ++j)
                p[j * 16] = (bf16)(acc[i][j][rg] * f);
        }
    }
}

// ---------------------------------------------------------------------------
// gemm2: out[32768,1024] = attn @ V'. Block: 128 rows x 512 cols, 512 thr,
// 8 waves (wave = 128r x 64c, acc[8][4]). B reg-direct (fragment order);
// A via global_load_lds into 4x8KB rotating buffers, 2-deep. One barrier
// per body. Grid 512 (%8==0) with XCD swizzle.
// ---------------------------------------------------------------------------
__global__ __launch_bounds__(512, 2) void gemm2_kernel(const bf16* __restrict__ A,
                                                       const bf16* __restrict__ Vb,
                                                       float* __restrict__ C) {
    __shared__ __align__(16) bf16 As[4][128 * 32];   // 32 KB

    const int cpx = gridDim.x >> 3;                  // 64
    const int l   = ((int)blockIdx.x & 7) * cpx + ((int)blockIdx.x >> 3);
    const int bx  = l & 1, by = l >> 1;              // 2 col-blocks, 256 rows

    const int tid  = threadIdx.x;
    const int wv   = tid >> 6, lane = tid & 63;
    const int lm   = lane & 15, g = lane >> 4;
    const int rowB = by * 128;

    // A staging: thread -> row sr (0..127), chunk sc (0..3, 8 bf16 each)
    const int sr = tid >> 2, sc = tid & 3;

    // B fragments: wave's h-tiles = bx*32 + wv*4 + j
    const bf16* vbase = Vb + (bx * 32 + wv * 4) * 512 + lane * 8;

    f32x4 acc[8][4] = {};
    bf16x8 bf0[4], bf1[4];

#define A_STAGE(BI, C0)                                                         \
    gload_lds16(A + (size_t)(rowB + sr) * 512 + (C0) * 32                       \
                  + ((sc ^ ((sr >> 1) & 3)) << 3),                              \
                (char*)As[BI] + wv * 1024);
#define B_PREF(DST, C0) { _Pragma("unroll") for (int j = 0; j < 4; ++j)         \
        gl_b16x8(DST[j], vbase + (size_t)(C0) * 32768 + j * 512); }
#define COMPUTE_G(BI, BF) { bf16x8 af[8];                                       \
    _Pragma("unroll") for (int i = 0; i < 8; ++i) { const int r = i * 16 + lm;  \
        af[i] = *(const bf16x8*)((const char*)As[BI] + r * 64                   \
                                 + ((g ^ ((r >> 1) & 3)) << 4)); }              \
    __builtin_amdgcn_s_setprio(1);                                              \
    _Pragma("unroll") for (int i = 0; i < 8; ++i)                               \
        _Pragma("unroll") for (int j = 0; j < 4; ++j)                           \
            acc[i][j] = __builtin_amdgcn_mfma_f32_16x16x32_bf16(                \
                af[i], BF[j], acc[i][j], 0, 0, 0);                              \
    __builtin_amdgcn_s_setprio(0); }
// steady body t: entry queue = [A(t+1)1, B(t)4]
#define STEP_G(BCUR, BNXT, T)                                                   \
    A_STAGE((T + 2) & 3, T + 2);   /* +1 */                                     \
    B_PREF(BNXT, T + 1);           /* +4 -> 10 */                               \
    VMWBAR(5);                     /* retire A(t+1)+B(t); barrier */            \
    COMPUTE_G((T) & 3, BCUR);

    // prologue: queue = [A0:1, A1:1, B0:4] = 6
    A_STAGE(0, 0);
    A_STAGE(1, 1);
    B_PREF(bf0, 0);
    // body 0: entry 6, +5 = 11 -> VMWBAR(5) retires A0,A1,B0 (6) -> steady
    for (int t = 0; t < 14; t += 2) {
        STEP_G(bf0, bf1, t);
        STEP_G(bf1, bf0, t + 1);
    }
    // body 14: stage only B15 (A16 doesn't exist); entry [A15:1, B14:4]
    B_PREF(bf1, 15);                 // -> 9
    VMWBAR(4);                       // retire A15 + B14
    COMPUTE_G(2, bf0);               // buffer 14&3 = 2
    // body 15
    VMW(0);                          // retire B15
    COMPUTE_G(3, bf1);               // buffer 15&3 = 3

#undef A_STAGE
#undef B_PREF
#undef COMPUTE_G
#undef STEP_G

    // C/D layout: col = j*16 + lm (within wave's 64-col slice), row = i*16+g*4+r
    const int c0 = bx * 512 + wv * 64 + lm;
    #pragma unroll
    for (int i = 0; i < 8; ++i) {
        #pragma unroll
        for (int j = 0; j < 4; ++j) {
            #pragma unroll
            for (int r = 0; r < 4; ++r)
                C[(size_t)(rowB + i * 16 + g * 4 + r) * DIMX + (c0 + j * 16)]
                    = acc[i][j][r];
        }
    }
}

// ---------------------------------------------------------------------------
extern "C" void kernel_launch(void* const* d_in, const int* in_sizes, int n_in,
                              void* d_out, int out_size, void* d_ws, size_t ws_size,
                              hipStream_t stream) {
    const float* x  = (const float*)d_in[0];
    const float* kr = (const float*)d_in[1];
    const float* ki = (const float*)d_in[2];
    const float* vr = (const float*)d_in[3];
    const float* vi = (const float*)d_in[4];
    float* out = (float*)d_out;

    char* ws = (char*)d_ws;
    bf16* Kb   = (bf16*)ws;                        // 1 MiB (fragment order)
    bf16* Vb   = (bf16*)(ws + 1048576);            // 1 MiB (fragment order)
    bf16* attn = (bf16*)(ws + 2097152);            // 32 MiB

    pack_kv_kernel<<<2048, 256, 0, stream>>>(kr, ki, vr, vi, Kb, Vb);
    energy_softmax_kernel<<<256, 512, 0, stream>>>(x, Kb, attn);
    gemm2_kernel<<<512, 512, 0, stream>>>(attn, Vb, out);
}

// Round 6
// 289.395 us; speedup vs baseline: 1.0427x; 1.0427x over previous
//
#include <hip/hip_runtime.h>

// ---------------------------------------------------------------------------
// HolographicMemory: out = softmax( x @ [Kr|Ki]^T * temp ) @ [Vr|Vi]
// v7: halve the k-step count (BK=64 periods, one barrier per period) at the
//     measured-best v5 geometry. Tests the "fixed per-step overhead" theory:
//     32 -> 16 periods (energy), 16 -> 8 periods (gemm2).
//   energy: 64r x 512c block, 4 waves (64r x 128c each, acc[4][8]);
//           K reg-direct double-buffer per sub-step; X 2x8KB LDS periods.
//   gemm2:  128x128 tile, 4 waves; 8x8KB A ring (global_load_lds);
//           B reg pairs double-buffered; XCD swizzle.
// ---------------------------------------------------------------------------

#define DIMX   1024
#define MEMN   512
#define NROWS  32768
#define TEMP   0.04419417382415922f  // 512^-0.5

typedef __bf16 bf16;
typedef __bf16 bf16x8 __attribute__((ext_vector_type(8)));
typedef float  f32x4  __attribute__((ext_vector_type(4)));

__device__ __forceinline__ void gload_lds16(const void* g, void* l) {
    __builtin_amdgcn_global_load_lds(
        (const __attribute__((address_space(1))) unsigned*)g,
        (__attribute__((address_space(3))) unsigned*)l,
        16, 0, 0);
}
__device__ __forceinline__ void gl_b16x8(bf16x8& d, const bf16* p) {
    asm volatile("global_load_dwordx4 %0, %1, off" : "=v"(d) : "v"(p));
}
__device__ __forceinline__ void gl_f32x4(f32x4& d, const float* p) {
    asm volatile("global_load_dwordx4 %0, %1, off" : "=v"(d) : "v"(p));
}
#define VMW(N)     do { asm volatile("s_waitcnt vmcnt(" #N ")" ::: "memory"); \
                        __builtin_amdgcn_sched_barrier(0); } while (0)
#define WAITBAR(N) do { asm volatile("s_waitcnt vmcnt(" #N ") lgkmcnt(0)\n\t" \
                        "s_barrier" ::: "memory");                            \
                        __builtin_amdgcn_sched_barrier(0); } while (0)
#define VMWBAR(N)  do { asm volatile("s_waitcnt vmcnt(" #N ")\n\t"            \
                        "s_barrier" ::: "memory");                            \
                        __builtin_amdgcn_sched_barrier(0); } while (0)

// ---- pack K' and V'^T in MFMA-fragment order (unchanged, verified) --------
// Kb_f[c][t][l][e]: element (row=t*16+lm, k=c*32+g*8+e) of K'=[Kr|Ki]
// Vb_f[c][t][l][e]: element (n=t*16+lm, k=c*32+g*8+e) of V'^T [1024][512]
__global__ __launch_bounds__(256) void pack_kv_kernel(const float* __restrict__ kr,
                                                      const float* __restrict__ ki,
                                                      const float* __restrict__ vr,
                                                      const float* __restrict__ vi,
                                                      bf16* __restrict__ Kb,
                                                      bf16* __restrict__ Vb) {
    const int idx = blockIdx.x * 256 + threadIdx.x;   // 0 .. 2^19-1
    const int e = idx & 7, l = (idx >> 3) & 63;
    const int lm = l & 15, g = l >> 4;
    {   // Kb_f
        const int t = (idx >> 9) & 31, c = idx >> 14;
        const int row = t * 16 + lm, k = c * 32 + g * 8 + e;
        const float v = (k < 512) ? kr[row * 512 + k] : ki[row * 512 + (k - 512)];
        Kb[idx] = (bf16)v;
    }
    {   // Vb_f
        const int t = (idx >> 9) & 63, c = idx >> 15;
        const int h = t * 16 + lm, m = c * 32 + g * 8 + e;
        const float v = (h < 512) ? vr[m * 512 + h] : vi[m * 512 + (h - 512)];
        Vb[idx] = (bf16)v;
    }
}

// ---------------------------------------------------------------------------
// Fused energy + softmax. 64r x 512c block, 256 thr (4 waves, 64r x 128c).
// 16 periods of BK=64 (two BK=32 sub-steps), ONE barrier per period.
// Period p entry queue: [K(2p):8, X(p+1):4] = 12.
// ---------------------------------------------------------------------------
__global__ __launch_bounds__(256, 2) void energy_softmax_kernel(
        const float* __restrict__ x,    // [32768][1024] fp32
        const bf16*  __restrict__ Kb,   // fragment-order, 1 MiB
        bf16* __restrict__ attn) {      // [32768][512] bf16 out
    __shared__ __align__(16) bf16 Xs[2][64 * 64];   // 2 x 8 KB
    __shared__ float red[64][4][2];

    const int tid  = threadIdx.x;
    const int wv   = tid >> 6, lane = tid & 63;
    const int lm   = lane & 15, g = lane >> 4;
    const int rowB = blockIdx.x * 64;

    // X staging: thread -> row sr (0..63), 16-fp32 slice sc (0..3)
    const int sr = tid >> 2, sc = tid & 3;
    const float* xsrc = x + (size_t)(rowB + sr) * DIMX + sc * 16;

    // K fragments: wave's col-tiles are Kb mem-tiles wv*8 + j
    const bf16* kbase = Kb + (wv * 8) * 512 + lane * 8;

    f32x4 acc[4][8] = {};
    f32x4 xa0, xa1, xa2, xa3;
    bf16x8 kfA[8], kfB[8];

#define K_PREF(DST, C) { _Pragma("unroll") for (int j = 0; j < 8; ++j)         \
        gl_b16x8(DST[j], kbase + (size_t)(C) * 16384 + j * 512); }
#define X_PREF(P) { gl_f32x4(xa0, xsrc + (P) * 64);                            \
                    gl_f32x4(xa1, xsrc + (P) * 64 + 4);                        \
                    gl_f32x4(xa2, xsrc + (P) * 64 + 8);                        \
                    gl_f32x4(xa3, xsrc + (P) * 64 + 12); }
#define X_WR(B) { bf16x8 w0, w1;                                               \
    w0[0]=(bf16)xa0[0]; w0[1]=(bf16)xa0[1]; w0[2]=(bf16)xa0[2]; w0[3]=(bf16)xa0[3]; \
    w0[4]=(bf16)xa1[0]; w0[5]=(bf16)xa1[1]; w0[6]=(bf16)xa1[2]; w0[7]=(bf16)xa1[3]; \
    w1[0]=(bf16)xa2[0]; w1[1]=(bf16)xa2[1]; w1[2]=(bf16)xa2[2]; w1[3]=(bf16)xa2[3]; \
    w1[4]=(bf16)xa3[0]; w1[5]=(bf16)xa3[1]; w1[6]=(bf16)xa3[2]; w1[7]=(bf16)xa3[3]; \
    *(bf16x8*)((char*)Xs[B] + sr * 128 + (((2 * sc)     ^ (sr & 7)) << 4)) = w0; \
    *(bf16x8*)((char*)Xs[B] + sr * 128 + (((2 * sc + 1) ^ (sr & 7)) << 4)) = w1; }
#define COMPUTE_E(PB, S, KF) { bf16x8 af[4];                                   \
    _Pragma("unroll") for (int i = 0; i < 4; ++i) { const int r = i * 16 + lm; \
        af[i] = *(const bf16x8*)((const char*)Xs[PB] + r * 128                 \
                                 + (((((S) * 4) + g) ^ (r & 7)) << 4)); }      \
    __builtin_amdgcn_s_setprio(1);                                             \
    _Pragma("unroll") for (int i = 0; i < 4; ++i)                              \
        _Pragma("unroll") for (int j = 0; j < 8; ++j)                          \
            acc[i][j] = __builtin_amdgcn_mfma_f32_16x16x32_bf16(               \
                af[i], KF[j], acc[i][j], 0, 0, 0);                             \
    __builtin_amdgcn_s_setprio(0); }

    // ---- prologue: publish Xs[0]; leave [K(0):8, X(1):4] in flight ---------
    X_PREF(0);                 // 4
    K_PREF(kfA, 0);            // +8 -> 12
    VMW(8);                    // retire X(0)
    X_WR(0);                   // Xs[0]
    X_PREF(1);                 // +4 -> 12
    WAITBAR(12);               // barrier-only; publish Xs[0]

    // ---- periods 0..13 ------------------------------------------------------
    for (int p = 0; p < 14; ++p) {
        const int pb = p & 1;
        K_PREF(kfB, 2 * p + 1);    // -> 20
        VMW(12);                   // retire K(2p)  [full-period coverage]
        COMPUTE_E(pb, 0, kfA);
        K_PREF(kfA, 2 * p + 2);    // -> 20
        VMW(8);                    // retire X(p+1) + K(2p+1)
        COMPUTE_E(pb, 1, kfB);
        X_WR(pb ^ 1);              // X(p+1) -> other buffer
        X_PREF(p + 2);             // -> 12
        WAITBAR(12);               // barrier-only; publish Xs[pb^1]
    }
    // ---- period 14 (pb=0): no X(16) -----------------------------------------
    K_PREF(kfB, 29);
    VMW(12);
    COMPUTE_E(0, 0, kfA);
    K_PREF(kfA, 30);
    VMW(8);                    // retire X(15) + K(29)
    COMPUTE_E(0, 1, kfB);
    X_WR(1);                   // X(15) -> Xs[1]
    WAITBAR(8);                // [K(30):8]; publish Xs[1]
    // ---- period 15 (pb=1) ---------------------------------------------------
    K_PREF(kfB, 31);           // -> 16
    VMW(8);                    // retire K(30)
    COMPUTE_E(1, 0, kfA);
    VMW(0);                    // retire K(31)
    COMPUTE_E(1, 1, kfB);

#undef K_PREF
#undef X_PREF
#undef X_WR
#undef COMPUTE_E

    // ---- softmax epilogue ---------------------------------------------------
    // C/D layout: col = j*16 + lm (+wv*128), row = i*16 + g*4 + reg.
    float fac[4][4];
    #pragma unroll
    for (int i = 0; i < 4; ++i) {
        #pragma unroll
        for (int rg = 0; rg < 4; ++rg) {
            float m = acc[i][0][rg] * TEMP;
            #pragma unroll
            for (int j = 1; j < 8; ++j) m = fmaxf(m, acc[i][j][rg] * TEMP);
            m = fmaxf(m, __shfl_xor(m, 1));
            m = fmaxf(m, __shfl_xor(m, 2));
            m = fmaxf(m, __shfl_xor(m, 4));
            m = fmaxf(m, __shfl_xor(m, 8));
            float s = 0.f;
            #pragma unroll
            for (int j = 0; j < 8; ++j) {
                const float v = __expf(acc[i][j][rg] * TEMP - m);
                acc[i][j][rg] = v;
                s += v;
            }
            s += __shfl_xor(s, 1);
            s += __shfl_xor(s, 2);
            s += __shfl_xor(s, 4);
            s += __shfl_xor(s, 8);
            const int rr = i * 16 + g * 4 + rg;
            if (lm == 0) { red[rr][wv][0] = m; red[rr][wv][1] = s; }
            fac[i][rg] = m;
        }
    }
    __syncthreads();
    #pragma unroll
    for (int i = 0; i < 4; ++i) {
        #pragma unroll
        for (int rg = 0; rg < 4; ++rg) {
            const int rr = i * 16 + g * 4 + rg;
            const float m0 = red[rr][0][0], s0 = red[rr][0][1];
            const float m1 = red[rr][1][0], s1 = red[rr][1][1];
            const float m2 = red[rr][2][0], s2 = red[rr][2][1];
            const float m3 = red[rr][3][0], s3 = red[rr][3][1];
            const float M  = fmaxf(fmaxf(m0, m1), fmaxf(m2, m3));
            const float S  = s0 * __expf(m0 - M) + s1 * __expf(m1 - M)
                           + s2 * __expf(m2 - M) + s3 * __expf(m3 - M);
            fac[i][rg] = __expf(fac[i][rg] - M) / S;
        }
    }
    #pragma unroll
    for (int i = 0; i < 4; ++i) {
        #pragma unroll
        for (int rg = 0; rg < 4; ++rg) {
            const size_t rr = (size_t)(rowB + i * 16 + g * 4 + rg);
            bf16* p = attn + rr * MEMN + wv * 128 + lm;
            const float f = fac[i][rg];
            #pragma unroll
            for (int j = 0; j < 8; ++j)
                p[j * 16] = (bf16)(acc[i][j][rg] * f);
        }
    }
}

// ---------------------------------------------------------------------------
// gemm2: out[32768,1024] = attn @ V'. 128x128 tile, 4 waves (2x2). 16 k-chunks
// grouped into 8 periods, ONE barrier per period. A: 8x8KB LDS ring via
// global_load_lds (staged 4-ahead, retired at period-end VMWBAR). B: fragment-
// order reg pairs, double-buffered (full-period coverage). XCD swizzle.
// Period p entry queue: [Bpair(2p,2p+1):8, Apair(2p+2,2p+3):4] = 12.
// ---------------------------------------------------------------------------
__global__ __launch_bounds__(256, 2) void gemm2_kernel(const bf16* __restrict__ A,
                                                       const bf16* __restrict__ Vb,
                                                       float* __restrict__ C) {
    __shared__ __align__(16) bf16 As[8][128 * 32];   // 64 KB

    const int cpx = gridDim.x >> 3;
    const int l   = ((int)blockIdx.x & 7) * cpx + ((int)blockIdx.x >> 3);
    const int bx  = l & 7, by = l >> 3;              // 8 col-blocks

    const int tid  = threadIdx.x;
    const int wave = tid >> 6, lane = tid & 63;
    const int lm   = lane & 15, g = lane >> 4;
    const int rowB = by * 128;
    const int wrow = (wave >> 1) * 64;

    const bf16* vbase = Vb + (bx * 8 + (wave & 1) * 4) * 512 + lane * 8;

    f32x4 acc[4][4] = {};
    bf16x8 bfA[4], bfB[4], bfC[4], bfD[4];

#define A_STAGE(BI, C0) { _Pragma("unroll") for (int li = 0; li < 2; ++li) {    \
        const int q = wave * 2 + li;                                            \
        const int r = q * 16 + (lane >> 2);                                     \
        const int ch = lane & 3;                                                \
        gload_lds16(A + (size_t)(rowB + r) * 512 + (C0) * 32                    \
                      + ((ch ^ ((r >> 1) & 3)) << 3),                           \
                    (char*)As[BI] + q * 1024); } }
#define B_PREF(DST, C0) { _Pragma("unroll") for (int j = 0; j < 4; ++j)         \
        gl_b16x8(DST[j], vbase + (size_t)(C0) * 32768 + j * 512); }
#define COMPUTE_G(BI, BF) { bf16x8 af[4];                                       \
    _Pragma("unroll") for (int i = 0; i < 4; ++i) {                             \
        const int r = wrow + i * 16 + lm;                                       \
        af[i] = *(const bf16x8*)((const char*)As[BI] + r * 64                   \
                                 + ((g ^ ((r >> 1) & 3)) << 4)); }              \
    __builtin_amdgcn_s_setprio(1);                                              \
    _Pragma("unroll") for (int i = 0; i < 4; ++i)                               \
        _Pragma("unroll") for (int j = 0; j < 4; ++j)                           \
            acc[i][j] = __builtin_amdgcn_mfma_f32_16x16x32_bf16(                \
                af[i], BF[j], acc[i][j], 0, 0, 0);                              \
    __builtin_amdgcn_s_setprio(0); }
#define PERIOD_G(P, C0F, C1F, N0F, N1F)                                         \
    B_PREF(N0F, 2 * (P) + 2);                                                   \
    B_PREF(N1F, 2 * (P) + 3);      /* -> 20 */                                  \
    VMW(12);                       /* retire Bpair(2p,2p+1) */                  \
    COMPUTE_G((2 * (P)) & 7, C0F);                                              \
    COMPUTE_G((2 * (P) + 1) & 7, C1F);                                          \
    A_STAGE((2 * (P) + 4) & 7, 2 * (P) + 4);                                    \
    A_STAGE((2 * (P) + 5) & 7, 2 * (P) + 5);   /* -> 16 */                      \
    VMWBAR(12);                    /* retire+publish Apair(2p+2,2p+3) */

    // ---- prologue: [Bpair(0,1):8, Apair(2,3):4] after publishing A(0,1) -----
    A_STAGE(0, 0);  A_STAGE(1, 1);     // 4
    B_PREF(bfA, 0); B_PREF(bfB, 1);    // +8 -> 12
    A_STAGE(2, 2);  A_STAGE(3, 3);     // +4 -> 16
    VMWBAR(12);                        // retire+publish A(0),A(1)

    // ---- periods 0..5 -------------------------------------------------------
    for (int p = 0; p < 6; p += 2) {
        PERIOD_G(p,     bfA, bfB, bfC, bfD);
        PERIOD_G(p + 1, bfC, bfD, bfA, bfB);
    }
    // ---- period 6: no A(16,17) ----------------------------------------------
    B_PREF(bfC, 14);
    B_PREF(bfD, 15);               // -> 20
    VMW(12);                       // retire Bpair(12,13)
    COMPUTE_G(4, bfA);             // chunk 12
    COMPUTE_G(5, bfB);             // chunk 13
    VMWBAR(8);                     // retire+publish Apair(14,15)
    // ---- period 7 -----------------------------------------------------------
    VMW(0);                        // retire Bpair(14,15)
    COMPUTE_G(6, bfC);             // chunk 14
    COMPUTE_G(7, bfD);             // chunk 15

#undef A_STAGE
#undef B_PREF
#undef COMPUTE_G
#undef PERIOD_G

    // C/D layout: col = lane&15 (+tiles), row = (lane>>4)*4 + reg
    const int r0 = rowB + wrow + g * 4;
    const int c0 = bx * 128 + (wave & 1) * 64 + lm;
    #pragma unroll
    for (int i = 0; i < 4; ++i) {
        #pragma unroll
        for (int j = 0; j < 4; ++j) {
            #pragma unroll
            for (int r = 0; r < 4; ++r)
                C[(size_t)(r0 + i * 16 + r) * DIMX + (c0 + j * 16)] = acc[i][j][r];
        }
    }
}

// ---------------------------------------------------------------------------
extern "C" void kernel_launch(void* const* d_in, const int* in_sizes, int n_in,
                              void* d_out, int out_size, void* d_ws, size_t ws_size,
                              hipStream_t stream) {
    const float* x  = (const float*)d_in[0];
    const float* kr = (const float*)d_in[1];
    const float* ki = (const float*)d_in[2];
    const float* vr = (const float*)d_in[3];
    const float* vi = (const float*)d_in[4];
    float* out = (float*)d_out;

    char* ws = (char*)d_ws;
    bf16* Kb   = (bf16*)ws;                        // 1 MiB (fragment order)
    bf16* Vb   = (bf16*)(ws + 1048576);            // 1 MiB (fragment order)
    bf16* attn = (bf16*)(ws + 2097152);            // 32 MiB

    pack_kv_kernel<<<2048, 256, 0, stream>>>(kr, ki, vr, vi, Kb, Vb);
    energy_softmax_kernel<<<512, 256, 0, stream>>>(x, Kb, attn);
    gemm2_kernel<<<2048, 256, 0, stream>>>(attn, Vb, out);
}

// Round 7
// 274.024 us; speedup vs baseline: 1.1012x; 1.0561x over previous
//
#include <hip/hip_runtime.h>

// ---------------------------------------------------------------------------
// HolographicMemory: out = softmax( x @ [Kr|Ki]^T * temp ) @ [Vr|Vi]
// v8: FULL FUSION. One compute kernel: energy GEMM (v7 structure, verified)
//     -> softmax -> P scattered to LDS (XOR-swizzled) -> PV GEMM with V'
//     fragment-direct from L2. No attn HBM round-trip, no device-wide sync
//     between the GEMMs, cross-phase overlap of the 2 resident blocks/CU.
// LDS overlay (64 KB): [Xs 16K | red 2K] during energy/softmax, P 64K for PV.
// ---------------------------------------------------------------------------

#define DIMX   1024
#define MEMN   512
#define NROWS  32768
#define TEMP   0.04419417382415922f  // 512^-0.5

typedef __bf16 bf16;
typedef __bf16 bf16x8 __attribute__((ext_vector_type(8)));
typedef float  f32x4  __attribute__((ext_vector_type(4)));

__device__ __forceinline__ void gl_b16x8(bf16x8& d, const bf16* p) {
    asm volatile("global_load_dwordx4 %0, %1, off" : "=v"(d) : "v"(p));
}
__device__ __forceinline__ void gl_f32x4(f32x4& d, const float* p) {
    asm volatile("global_load_dwordx4 %0, %1, off" : "=v"(d) : "v"(p));
}
#define VMW(N)     do { asm volatile("s_waitcnt vmcnt(" #N ")" ::: "memory"); \
                        __builtin_amdgcn_sched_barrier(0); } while (0)
#define WAITBAR(N) do { asm volatile("s_waitcnt vmcnt(" #N ") lgkmcnt(0)\n\t" \
                        "s_barrier" ::: "memory");                            \
                        __builtin_amdgcn_sched_barrier(0); } while (0)

// ---- pack K' and V'^T in MFMA-fragment order (verified r3-r6) -------------
// Kb_f[c][t][l][e]: element (row=t*16+lm, k=c*32+g*8+e) of K'=[Kr|Ki]
// Vb_f[c][t][l][e]: element (h=t*16+lm, mem=c*32+g*8+e) of V'^T [1024][512]
__global__ __launch_bounds__(256) void pack_kv_kernel(const float* __restrict__ kr,
                                                      const float* __restrict__ ki,
                                                      const float* __restrict__ vr,
                                                      const float* __restrict__ vi,
                                                      bf16* __restrict__ Kb,
                                                      bf16* __restrict__ Vb) {
    const int idx = blockIdx.x * 256 + threadIdx.x;   // 0 .. 2^19-1
    const int e = idx & 7, l = (idx >> 3) & 63;
    const int lm = l & 15, g = l >> 4;
    {   // Kb_f
        const int t = (idx >> 9) & 31, c = idx >> 14;
        const int row = t * 16 + lm, k = c * 32 + g * 8 + e;
        const float v = (k < 512) ? kr[row * 512 + k] : ki[row * 512 + (k - 512)];
        Kb[idx] = (bf16)v;
    }
    {   // Vb_f
        const int t = (idx >> 9) & 63, c = idx >> 15;
        const int h = t * 16 + lm, m = c * 32 + g * 8 + e;
        const float v = (h < 512) ? vr[m * 512 + h] : vi[m * 512 + (h - 512)];
        Vb[idx] = (bf16)v;
    }
}

// ---------------------------------------------------------------------------
// Fused kernel. Block = 64 x-rows, 256 thr (4 waves), grid 512 (2 blocks/CU).
// Phase 1 (energy, v7-verified): wave wv owns cols wv*128..+127 -> acc[4][8].
// Phase 2: softmax (per-wave partials + LDS combine).
// Phase 3: P[64][512] bf16 -> LDS, chunk-XOR swizzle byte^=((row&7)<<4).
// Phase 4: PV. wave wv owns out cols wv*256..+255, two 128-col halves with
//          acc reuse; A-frags from P_lds (2-way banked), B-frags = Vb_f
//          direct from L2, double-buffered regs, counted vmcnt.
// ---------------------------------------------------------------------------
__global__ __launch_bounds__(256, 2) void fused_kernel(
        const float* __restrict__ x,    // [32768][1024] fp32
        const bf16*  __restrict__ Kb,   // fragment-order, 1 MiB
        const bf16*  __restrict__ Vb,   // fragment-order, 1 MiB
        float* __restrict__ out) {      // [32768][1024] fp32
    __shared__ __align__(16) char smem[65536];
    // overlay: energy uses [0,16384) = Xs[2][64*64], [16384,18432) = red;
    //          PV uses [0,65536) = P[64][512] bf16 (chunk-swizzled)
    float (*red)[4][2] = (float (*)[4][2])(smem + 16384);
    char* Pl = smem;

    const int tid  = threadIdx.x;
    const int wv   = tid >> 6, lane = tid & 63;
    const int lm   = lane & 15, g = lane >> 4;
    const int rowB = blockIdx.x * 64;

    // X staging: thread -> row sr (0..63), 16-fp32 slice sc (0..3)
    const int sr = tid >> 2, sc = tid & 3;
    const float* xsrc = x + (size_t)(rowB + sr) * DIMX + sc * 16;

    const bf16* kbase = Kb + (wv * 8) * 512 + lane * 8;

    f32x4 acc[4][8] = {};
    f32x4 xa0, xa1, xa2, xa3;
    bf16x8 kfA[8], kfB[8];

#define K_PREF(DST, C) { _Pragma("unroll") for (int j = 0; j < 8; ++j)         \
        gl_b16x8(DST[j], kbase + (size_t)(C) * 16384 + j * 512); }
#define X_PREF(P) { gl_f32x4(xa0, xsrc + (P) * 64);                            \
                    gl_f32x4(xa1, xsrc + (P) * 64 + 4);                        \
                    gl_f32x4(xa2, xsrc + (P) * 64 + 8);                        \
                    gl_f32x4(xa3, xsrc + (P) * 64 + 12); }
#define X_WR(B) { bf16x8 w0, w1;                                               \
    w0[0]=(bf16)xa0[0]; w0[1]=(bf16)xa0[1]; w0[2]=(bf16)xa0[2]; w0[3]=(bf16)xa0[3]; \
    w0[4]=(bf16)xa1[0]; w0[5]=(bf16)xa1[1]; w0[6]=(bf16)xa1[2]; w0[7]=(bf16)xa1[3]; \
    w1[0]=(bf16)xa2[0]; w1[1]=(bf16)xa2[1]; w1[2]=(bf16)xa2[2]; w1[3]=(bf16)xa2[3]; \
    w1[4]=(bf16)xa3[0]; w1[5]=(bf16)xa3[1]; w1[6]=(bf16)xa3[2]; w1[7]=(bf16)xa3[3]; \
    *(bf16x8*)(smem + (B) * 8192 + sr * 128 + (((2 * sc)     ^ (sr & 7)) << 4)) = w0; \
    *(bf16x8*)(smem + (B) * 8192 + sr * 128 + (((2 * sc + 1) ^ (sr & 7)) << 4)) = w1; }
#define COMPUTE_E(PB, S, KF) { bf16x8 af[4];                                   \
    _Pragma("unroll") for (int i = 0; i < 4; ++i) { const int r = i * 16 + lm; \
        af[i] = *(const bf16x8*)(smem + (PB) * 8192 + r * 128                  \
                                 + (((((S) * 4) + g) ^ (r & 7)) << 4)); }      \
    __builtin_amdgcn_s_setprio(1);                                             \
    _Pragma("unroll") for (int i = 0; i < 4; ++i)                              \
        _Pragma("unroll") for (int j = 0; j < 8; ++j)                          \
            acc[i][j] = __builtin_amdgcn_mfma_f32_16x16x32_bf16(               \
                af[i], KF[j], acc[i][j], 0, 0, 0);                             \
    __builtin_amdgcn_s_setprio(0); }

    // ---- energy prologue ----------------------------------------------------
    X_PREF(0);                 // 4
    K_PREF(kfA, 0);            // +8 -> 12
    VMW(8);                    // retire X(0)
    X_WR(0);
    X_PREF(1);                 // -> 12
    WAITBAR(12);               // barrier-only; publish Xs[0]

    // ---- energy periods 0..13 (BK=64, one barrier per period) ---------------
    for (int p = 0; p < 14; ++p) {
        const int pb = p & 1;
        K_PREF(kfB, 2 * p + 1);    // -> 20
        VMW(12);                   // retire K(2p)
        COMPUTE_E(pb, 0, kfA);
        K_PREF(kfA, 2 * p + 2);    // -> 20
        VMW(8);                    // retire X(p+1) + K(2p+1)
        COMPUTE_E(pb, 1, kfB);
        X_WR(pb ^ 1);
        X_PREF(p + 2);             // -> 12
        WAITBAR(12);               // barrier-only
    }
    // ---- period 14 ----------------------------------------------------------
    K_PREF(kfB, 29);
    VMW(12);
    COMPUTE_E(0, 0, kfA);
    K_PREF(kfA, 30);
    VMW(8);
    COMPUTE_E(0, 1, kfB);
    X_WR(1);
    WAITBAR(8);
    // ---- period 15 ----------------------------------------------------------
    K_PREF(kfB, 31);
    VMW(8);
    COMPUTE_E(1, 0, kfA);
    VMW(0);                    // all VM retired before softmax
    COMPUTE_E(1, 1, kfB);

#undef K_PREF
#undef X_PREF
#undef X_WR
#undef COMPUTE_E

    // ---- softmax ------------------------------------------------------------
    // C/D layout: col = j*16 + lm (+wv*128), row = i*16 + g*4 + reg.
    float fac[4][4];
    #pragma unroll
    for (int i = 0; i < 4; ++i) {
        #pragma unroll
        for (int rg = 0; rg < 4; ++rg) {
            float m = acc[i][0][rg] * TEMP;
            #pragma unroll
            for (int j = 1; j < 8; ++j) m = fmaxf(m, acc[i][j][rg] * TEMP);
            m = fmaxf(m, __shfl_xor(m, 1));
            m = fmaxf(m, __shfl_xor(m, 2));
            m = fmaxf(m, __shfl_xor(m, 4));
            m = fmaxf(m, __shfl_xor(m, 8));
            float s = 0.f;
            #pragma unroll
            for (int j = 0; j < 8; ++j) {
                const float v = __expf(acc[i][j][rg] * TEMP - m);
                acc[i][j][rg] = v;
                s += v;
            }
            s += __shfl_xor(s, 1);
            s += __shfl_xor(s, 2);
            s += __shfl_xor(s, 4);
            s += __shfl_xor(s, 8);
            const int rr = i * 16 + g * 4 + rg;
            if (lm == 0) { red[rr][wv][0] = m; red[rr][wv][1] = s; }
            fac[i][rg] = m;
        }
    }
    __syncthreads();           // red published
    #pragma unroll
    for (int i = 0; i < 4; ++i) {
        #pragma unroll
        for (int rg = 0; rg < 4; ++rg) {
            const int rr = i * 16 + g * 4 + rg;
            const float m0 = red[rr][0][0], s0 = red[rr][0][1];
            const float m1 = red[rr][1][0], s1 = red[rr][1][1];
            const float m2 = red[rr][2][0], s2 = red[rr][2][1];
            const float m3 = red[rr][3][0], s3 = red[rr][3][1];
            const float M  = fmaxf(fmaxf(m0, m1), fmaxf(m2, m3));
            const float S  = s0 * __expf(m0 - M) + s1 * __expf(m1 - M)
                           + s2 * __expf(m2 - M) + s3 * __expf(m3 - M);
            fac[i][rg] = __expf(fac[i][rg] - M) / S;
        }
    }
    __syncthreads();           // red reads done -> safe to overwrite with P

    // ---- scatter P -> LDS (chunk-XOR swizzle) -------------------------------
    // P byte addr: row*1024 + ((col>>3 ^ (row&7))<<4) + (col&7)*2
    {
        const int cb = wv * 16 + (lm >> 3);   // col>>3 = cb + j*2
        const int ce = (lm & 7) * 2;
        #pragma unroll
        for (int i = 0; i < 4; ++i) {
            #pragma unroll
            for (int rg = 0; rg < 4; ++rg) {
                const int row = i * 16 + g * 4 + rg;
                const int rx  = row & 7;
                const float f = fac[i][rg];
                char* prow = Pl + row * 1024 + ce;
                #pragma unroll
                for (int j = 0; j < 8; ++j)
                    *(bf16*)(prow + (((cb + j * 2) ^ rx) << 4))
                        = (bf16)(acc[i][j][rg] * f);
            }
        }
    }
    __syncthreads();           // P visible to all waves

    // ---- PV: out[64][1024] = P @ V', wave owns cols wv*256..+255 ------------
#define PV_COMPUTE(BF, KS) { bf16x8 af[4];                                     \
    _Pragma("unroll") for (int i = 0; i < 4; ++i) { const int r = i * 16 + lm; \
        af[i] = *(const bf16x8*)(Pl + r * 1024                                 \
                                 + ((((KS) * 4 + g) ^ (r & 7)) << 4)); }       \
    __builtin_amdgcn_s_setprio(1);                                             \
    _Pragma("unroll") for (int i = 0; i < 4; ++i)                              \
        _Pragma("unroll") for (int j = 0; j < 8; ++j)                          \
            acc[i][j] = __builtin_amdgcn_mfma_f32_16x16x32_bf16(               \
                af[i], BF[j], acc[i][j], 0, 0, 0);                             \
    __builtin_amdgcn_s_setprio(0); }
#define V_PREF(DST, KS) { _Pragma("unroll") for (int j = 0; j < 8; ++j)        \
        gl_b16x8(DST[j], vb + (size_t)(KS) * 32768 + j * 512); }

    #pragma unroll
    for (int h = 0; h < 2; ++h) {
        #pragma unroll
        for (int i = 0; i < 4; ++i)
            #pragma unroll
            for (int j = 0; j < 8; ++j)
                acc[i][j] = (f32x4){0.f, 0.f, 0.f, 0.f};

        const bf16* vb = Vb + (size_t)(wv * 16 + h * 8) * 512 + lane * 8;
        bf16x8 bv0[8], bv1[8];
        V_PREF(bv0, 0);
        for (int ks = 0; ks < 14; ks += 2) {
            V_PREF(bv1, ks + 1); VMW(8); PV_COMPUTE(bv0, ks);
            V_PREF(bv0, ks + 2); VMW(8); PV_COMPUTE(bv1, ks + 1);
        }
        V_PREF(bv1, 15); VMW(8); PV_COMPUTE(bv0, 14);
        VMW(0);          PV_COMPUTE(bv1, 15);

        // store half: rows rowB+i*16+g*4+rg, cols wv*256 + h*128 + j*16 + lm
        const int c0 = wv * 256 + h * 128 + lm;
        #pragma unroll
        for (int i = 0; i < 4; ++i) {
            #pragma unroll
            for (int j = 0; j < 8; ++j) {
                #pragma unroll
                for (int rg = 0; rg < 4; ++rg)
                    out[(size_t)(rowB + i * 16 + g * 4 + rg) * DIMX
                        + (c0 + j * 16)] = acc[i][j][rg];
            }
        }
    }

#undef PV_COMPUTE
#undef V_PREF
}

// ---------------------------------------------------------------------------
extern "C" void kernel_launch(void* const* d_in, const int* in_sizes, int n_in,
                              void* d_out, int out_size, void* d_ws, size_t ws_size,
                              hipStream_t stream) {
    const float* x  = (const float*)d_in[0];
    const float* kr = (const float*)d_in[1];
    const float* ki = (const float*)d_in[2];
    const float* vr = (const float*)d_in[3];
    const float* vi = (const float*)d_in[4];
    float* out = (float*)d_out;

    char* ws = (char*)d_ws;
    bf16* Kb = (bf16*)ws;                  // 1 MiB (fragment order)
    bf16* Vb = (bf16*)(ws + 1048576);      // 1 MiB (fragment order)

    pack_kv_kernel<<<2048, 256, 0, stream>>>(kr, ki, vr, vi, Kb, Vb);
    fused_kernel<<<512, 256, 0, stream>>>(x, Kb, Vb, out);
}